// Round 2
// baseline (874.635 us; speedup 1.0000x reference)
//
#include <hip/hip_runtime.h>

#define NR 64          // NX == NY
#define NH 256         // H
#define NP1 65
#define NITER 20

typedef _Float16 f16x8 __attribute__((ext_vector_type(8)));
typedef _Float16 f16x4 __attribute__((ext_vector_type(4)));
typedef float f32x4t __attribute__((ext_vector_type(4)));

__device__ __forceinline__ float dot4(float4 a, float4 b) {
  return a.x * b.x + a.y * b.y + a.z * b.z + a.w * b.w;
}

__global__ __launch_bounds__(256, 6)
void sinkhorn_kernel(const float* __restrict__ x, const float* __restrict__ y,
                     const float* __restrict__ gam, const float* __restrict__ bet,
                     const float* __restrict__ wdb, const float* __restrict__ bdb,
                     float* __restrict__ out_match, float* __restrict__ out_score)
{
  const int b    = blockIdx.x;
  const int t    = threadIdx.x;
  const int lane = t & 63;
  const int wvid = t >> 6;      // wave 0..3
  const int ti   = t >> 4;      // 0..15
  const int tj   = t & 15;      // 0..15
  const int i0   = ti * 4, j0 = tj * 4;
  const int ql   = lane >> 4;   // quarter within wave 0..3
  const int pl   = lane & 15;

  // s_buf phases:
  //  P1: As (f16 [64][64] xor-swizzled, 8KB) | Bs (8KB)
  //  P2: Cf f32 [64][68] = floats 0..4351 (aliases As/Bs)
  //  P3: vp[2][4][64] at 4352, vp64[2][4] at 4864 (disjoint from Cf)
  //  P4: Om[65*65] output staging (aliases Cf)
  __shared__ __align__(16) float s_buf[4872];   // 19.5 KB
  __shared__ __align__(16) float s_gw[NH];
  __shared__ __align__(16) float s_sx[NR], s_ax[NR], s_sy[NR], s_ay[NR];
  __shared__ float s_red[8];
  __shared__ float s_S12[2];

  _Float16* As = (_Float16*)s_buf;            // 4096 f16
  _Float16* Bs = (_Float16*)s_buf + 4096;
  float* Cf   = s_buf;                        // [64][68]
  float* vp   = s_buf + 4352;                 // [2][4][64]
  float* vp64 = s_buf + 4864;                 // [2][4]
  float* Om   = s_buf;                        // [4225]

  const float norm_c  = -4.852030263919617f;    // -log(128); exp = 1/128
  const float logmu64 = -0.6931471805599453f;   // -log2; exp = 0.5

  // ---------------- phase 0: gw = gamma*w, S1 = sum(gw), S2 = sum(beta*w)+b
  {
    float gv = gam[t];
    float wv = wdb[t];
    float p1 = gv * wv;
    float p2 = bet[t] * wv;
    s_gw[t] = p1;
    #pragma unroll
    for (int o = 1; o < 64; o <<= 1) { p1 += __shfl_xor(p1, o); p2 += __shfl_xor(p2, o); }
    if (lane == 0) { s_red[wvid * 2] = p1; s_red[wvid * 2 + 1] = p2; }
  }
  __syncthreads();
  if (t == 0) {
    s_S12[0] = s_red[0] + s_red[2] + s_red[4] + s_red[6];
    s_S12[1] = s_red[1] + s_red[3] + s_red[5] + s_red[7] + bdb[0];
  }

  // ---------------- phase 1: load + stats (f32) + f16 staging + MFMA
  float xsum[4] = {}, xsq[4] = {}, xdg[4] = {};
  float ysum[4] = {}, ysq[4] = {}, ydg[4] = {};
  f32x4t acc4[4];
  #pragma unroll
  for (int ct = 0; ct < 4; ++ct) {
    #pragma unroll
    for (int r = 0; r < 4; ++r) acc4[ct][r] = 0.0f;
  }

  const size_t gbase = (size_t)b * NR * NH;
  const int lh4 = tj * 4;      // h-offset within 64-float chunk

  for (int ch = 0; ch < 4; ++ch) {
    __syncthreads();   // previous chunk's fragment reads done before overwrite
    const float4 gw4 = *(const float4*)(s_gw + ch * 64 + lh4);
    #pragma unroll
    for (int j = 0; j < 4; ++j) {
      const int row  = ti + 16 * j;
      const int blk  = (tj >> 1) ^ (row & 7);          // xor-swizzled 16B block
      const int boff = row * 128 + blk * 16 + (tj & 1) * 8;
      const float4 xv = *(const float4*)(x + gbase + (size_t)row * NH + ch * 64 + lh4);
      xsum[j] += xv.x + xv.y + xv.z + xv.w;
      xsq[j]  += dot4(xv, xv);
      xdg[j]  += dot4(xv, gw4);
      f16x4 xh;
      xh[0] = (_Float16)xv.x; xh[1] = (_Float16)xv.y;
      xh[2] = (_Float16)xv.z; xh[3] = (_Float16)xv.w;
      *(f16x4*)((char*)As + boff) = xh;
      const float4 yv = *(const float4*)(y + gbase + (size_t)row * NH + ch * 64 + lh4);
      ysum[j] += yv.x + yv.y + yv.z + yv.w;
      ysq[j]  += dot4(yv, yv);
      ydg[j]  += dot4(yv, gw4);
      f16x4 yh;
      yh[0] = (_Float16)yv.x; yh[1] = (_Float16)yv.y;
      yh[2] = (_Float16)yv.z; yh[3] = (_Float16)yv.w;
      *(f16x4*)((char*)Bs + boff) = yh;
    }
    __syncthreads();
    // wave wvid: A rows 16w..16w+15, all 64 cols, K-steps of 32 within the chunk
    #pragma unroll
    for (int s = 0; s < 2; ++s) {
      const int arow = 16 * wvid + pl;
      const int kb   = 4 * s + ql;                     // 16B-block index in row
      const int ab   = kb ^ (pl & 7);                  // arow&7 == pl&7
      const f16x8 af = *(const f16x8*)((char*)As + arow * 128 + ab * 16);
      #pragma unroll
      for (int ct = 0; ct < 4; ++ct) {
        const int bcol = 16 * ct + pl;
        const f16x8 bf = *(const f16x8*)((char*)Bs + bcol * 128 + ab * 16);
        acc4[ct] = __builtin_amdgcn_mfma_f32_16x16x32_f16(af, bf, acc4[ct], 0, 0, 0);
      }
    }
  }

  // reduce stats across the 16 tj lanes sharing the same row set
  #pragma unroll
  for (int o = 1; o < 16; o <<= 1) {
    #pragma unroll
    for (int j = 0; j < 4; ++j) {
      xsum[j] += __shfl_xor(xsum[j], o);
      xsq[j]  += __shfl_xor(xsq[j], o);
      xdg[j]  += __shfl_xor(xdg[j], o);
      ysum[j] += __shfl_xor(ysum[j], o);
      ysq[j]  += __shfl_xor(ysq[j], o);
      ydg[j]  += __shfl_xor(ydg[j], o);
    }
  }
  if (tj == 0) {
    const float S1 = s_S12[0], S2 = s_S12[1];
    #pragma unroll
    for (int j = 0; j < 4; ++j) {
      const int r = ti + 16 * j;
      float mu   = xsum[j] * (1.0f / NH);
      float var  = xsq[j] * (1.0f / NH) - mu * mu;
      float rstd = rsqrtf(var + 1e-5f);
      s_ax[r] = tanhf(rstd * (xdg[j] - mu * S1) + S2);
      s_sx[r] = 1.0f / fmaxf(sqrtf(xsq[j]), 1e-12f);
      mu   = ysum[j] * (1.0f / NH);
      var  = ysq[j] * (1.0f / NH) - mu * mu;
      rstd = rsqrtf(var + 1e-5f);
      s_ay[r] = tanhf(rstd * (ydg[j] - mu * S1) + S2);
      s_sy[r] = 1.0f / fmaxf(sqrtf(ysq[j]), 1e-12f);
    }
  }
  __syncthreads();   // stats visible; all fragment reads complete -> alias Cf

  // ---------------- scatter MFMA accumulators: D col=lane&15, row=(lane>>4)*4+reg
  #pragma unroll
  for (int ct = 0; ct < 4; ++ct) {
    #pragma unroll
    for (int r = 0; r < 4; ++r) {
      Cf[(16 * wvid + 4 * ql + r) * 68 + 16 * ct + pl] = acc4[ct][r];
    }
  }
  __syncthreads();

  // ---------------- gather 4x4 tile; C = couplings/reg and E = exp(C) in regs
  const float4 sx4 = *(const float4*)(s_sx + i0);
  const float4 sy4 = *(const float4*)(s_sy + j0);
  const float4 ax4 = *(const float4*)(s_ax + i0);
  const float4 ay4 = *(const float4*)(s_ay + j0);
  const float sxr[4] = {sx4.x, sx4.y, sx4.z, sx4.w};
  const float syc[4] = {sy4.x, sy4.y, sy4.z, sy4.w};
  float C[4][4], E[4][4];
  #pragma unroll
  for (int r = 0; r < 4; ++r) {
    const float4 c4 = *(const float4*)(Cf + (i0 + r) * 68 + j0);
    const float cr[4] = {c4.x, c4.y, c4.z, c4.w};
    #pragma unroll
    for (int c = 0; c < 4; ++c) {
      C[r][c] = cr[c] * sxr[r] * syc[c] * 10.0f;   // /REG
      E[r][c] = __expf(C[r][c]);
    }
  }
  const float exi64[4] = {__expf(10.0f * ax4.x), __expf(10.0f * ax4.y),
                          __expf(10.0f * ax4.z), __expf(10.0f * ax4.w)};
  const float ey64[4]  = {__expf(10.0f * ay4.x), __expf(10.0f * ay4.y),
                          __expf(10.0f * ay4.z), __expf(10.0f * ay4.w)};

  // ---------------- Sinkhorn: 20 iterations, all state in registers.
  float ev_c[4] = {1.0f, 1.0f, 1.0f, 1.0f};
  float ev64 = 1.0f;
  float eu_r[4];
  float eu64 = 1.0f;
  float su_s[4], p64_s, sv_s[4], rs_s;
  int bufo = 0;

  #pragma unroll 2
  for (int it = 0; it < NITER; ++it) {
    // ---- u update (exp domain)
    float s0 = E[0][0] * ev_c[0] + E[0][1] * ev_c[1] + E[0][2] * ev_c[2] + E[0][3] * ev_c[3];
    float s1 = E[1][0] * ev_c[0] + E[1][1] * ev_c[1] + E[1][2] * ev_c[2] + E[1][3] * ev_c[3];
    float s2 = E[2][0] * ev_c[0] + E[2][1] * ev_c[1] + E[2][2] * ev_c[2] + E[2][3] * ev_c[3];
    float s3 = E[3][0] * ev_c[0] + E[3][1] * ev_c[1] + E[3][2] * ev_c[2] + E[3][3] * ev_c[3];
    float p64 = ey64[0] * ev_c[0] + ey64[1] * ev_c[1] + ey64[2] * ev_c[2] + ey64[3] * ev_c[3];
    #pragma unroll
    for (int o = 1; o < 16; o <<= 1) {
      s0  += __shfl_xor(s0, o);
      s1  += __shfl_xor(s1, o);
      s2  += __shfl_xor(s2, o);
      s3  += __shfl_xor(s3, o);
      p64 += __shfl_xor(p64, o);
    }
    su_s[0] = s0 + exi64[0] * ev64;
    su_s[1] = s1 + exi64[1] * ev64;
    su_s[2] = s2 + exi64[2] * ev64;
    su_s[3] = s3 + exi64[3] * ev64;
    p64_s = p64;
    eu_r[0] = 0.0078125f * __builtin_amdgcn_rcpf(su_s[0]);
    eu_r[1] = 0.0078125f * __builtin_amdgcn_rcpf(su_s[1]);
    eu_r[2] = 0.0078125f * __builtin_amdgcn_rcpf(su_s[2]);
    eu_r[3] = 0.0078125f * __builtin_amdgcn_rcpf(su_s[3]);
    eu64    = 0.5f       * __builtin_amdgcn_rcpf(p64);

    // ---- v update
    float q0 = E[0][0] * eu_r[0] + E[1][0] * eu_r[1] + E[2][0] * eu_r[2] + E[3][0] * eu_r[3];
    float q1 = E[0][1] * eu_r[0] + E[1][1] * eu_r[1] + E[2][1] * eu_r[2] + E[3][1] * eu_r[3];
    float q2 = E[0][2] * eu_r[0] + E[1][2] * eu_r[1] + E[2][2] * eu_r[2] + E[3][2] * eu_r[3];
    float q3 = E[0][3] * eu_r[0] + E[1][3] * eu_r[1] + E[2][3] * eu_r[2] + E[3][3] * eu_r[3];
    float r64 = exi64[0] * eu_r[0] + exi64[1] * eu_r[1] + exi64[2] * eu_r[2] + exi64[3] * eu_r[3];
    #pragma unroll
    for (int o = 16; o < 64; o <<= 1) {
      q0  += __shfl_xor(q0, o);
      q1  += __shfl_xor(q1, o);
      q2  += __shfl_xor(q2, o);
      q3  += __shfl_xor(q3, o);
      r64 += __shfl_xor(r64, o);
    }
    if ((t & 48) == 0) {   // one 16-lane slice per wave writes the wave partial
      *(float4*)(vp + (bufo * 4 + wvid) * 64 + j0) = make_float4(q0, q1, q2, q3);
      if (tj == 0) vp64[bufo * 4 + wvid] = r64;
    }
    __syncthreads();
    float sv0 = 0.0f, sv1 = 0.0f, sv2 = 0.0f, sv3 = 0.0f;
    #pragma unroll
    for (int w = 0; w < 4; ++w) {
      const float4 qq = *(const float4*)(vp + (bufo * 4 + w) * 64 + j0);
      sv0 += qq.x; sv1 += qq.y; sv2 += qq.z; sv3 += qq.w;
    }
    const float4 rr4 = *(const float4*)(vp64 + bufo * 4);
    rs_s = rr4.x + rr4.y + rr4.z + rr4.w;
    sv_s[0] = sv0 + ey64[0] * eu64;
    sv_s[1] = sv1 + ey64[1] * eu64;
    sv_s[2] = sv2 + ey64[2] * eu64;
    sv_s[3] = sv3 + ey64[3] * eu64;
    ev_c[0] = 0.0078125f * __builtin_amdgcn_rcpf(sv_s[0]);
    ev_c[1] = 0.0078125f * __builtin_amdgcn_rcpf(sv_s[1]);
    ev_c[2] = 0.0078125f * __builtin_amdgcn_rcpf(sv_s[2]);
    ev_c[3] = 0.0078125f * __builtin_amdgcn_rcpf(sv_s[3]);
    ev64    = 0.5f       * __builtin_amdgcn_rcpf(rs_s);
    bufo ^= 1;
  }

  // final u, v in log domain
  float u_r[4], v_c[4];
  #pragma unroll
  for (int r = 0; r < 4; ++r) u_r[r] = norm_c - __logf(su_s[r]);
  #pragma unroll
  for (int c = 0; c < 4; ++c) v_c[c] = norm_c - __logf(sv_s[c]);
  const float u64 = logmu64 - __logf(p64_s);
  const float v64 = logmu64 - __logf(rs_s);

  // ---------------- stage matching tile in LDS (Om aliases Cf; long dead) + score
  float sacc = 0.0f;
  #pragma unroll
  for (int r = 0; r < 4; ++r) {
    #pragma unroll
    for (int c = 0; c < 4; ++c) {
      const float m = C[r][c] + u_r[r] + v_c[c] - norm_c;
      Om[(i0 + r) * NP1 + (j0 + c)] = m;
      sacc += __expf(m) * C[r][c];   // scores/temp == C (reg==temp)
    }
  }
  if (t < 16) {   // dustbin row 64: thread t owns cols 4t..4t+3 (== j0 here)
    Om[64 * NP1 + j0 + 0] = 10.0f * ay4.x + u64 + v_c[0] - norm_c;
    Om[64 * NP1 + j0 + 1] = 10.0f * ay4.y + u64 + v_c[1] - norm_c;
    Om[64 * NP1 + j0 + 2] = 10.0f * ay4.z + u64 + v_c[2] - norm_c;
    Om[64 * NP1 + j0 + 3] = 10.0f * ay4.w + u64 + v_c[3] - norm_c;
  }
  if (tj == 0) {  // dustbin col 64: rows i0..i0+3
    Om[(i0 + 0) * NP1 + 64] = 10.0f * ax4.x + u_r[0] + v64 - norm_c;
    Om[(i0 + 1) * NP1 + 64] = 10.0f * ax4.y + u_r[1] + v64 - norm_c;
    Om[(i0 + 2) * NP1 + 64] = 10.0f * ax4.z + u_r[2] + v64 - norm_c;
    Om[(i0 + 3) * NP1 + 64] = 10.0f * ax4.w + u_r[3] + v64 - norm_c;
  }
  if (t == 0) {
    Om[64 * NP1 + 64] = -1000.0f + u64 + v64 - norm_c;
  }

  #pragma unroll
  for (int o = 1; o < 64; o <<= 1) sacc += __shfl_xor(sacc, o);
  if (lane == 0) s_red[wvid] = sacc;
  __syncthreads();   // Om + s_red visible

  // coalesced, full-line copy to global
  const size_t mbase = (size_t)b * (size_t)(NP1 * NP1);
  for (int idx = t; idx < NP1 * NP1; idx += 256) {
    out_match[mbase + idx] = Om[idx];
  }
  if (t == 0) out_score[b] = s_red[0] + s_red[1] + s_red[2] + s_red[3];
}

extern "C" void kernel_launch(void* const* d_in, const int* in_sizes, int n_in,
                              void* d_out, int out_size, void* d_ws, size_t ws_size,
                              hipStream_t stream) {
  const float* x   = (const float*)d_in[0];
  const float* y   = (const float*)d_in[1];
  const float* gam = (const float*)d_in[2];
  const float* bet = (const float*)d_in[3];
  const float* wdb = (const float*)d_in[4];
  const float* bdb = (const float*)d_in[5];
  float* out_match = (float*)d_out;
  float* out_score = (float*)d_out + (size_t)4096 * 4225;
  sinkhorn_kernel<<<4096, 256, 0, stream>>>(x, y, gam, bet, wdb, bdb, out_match, out_score);
}

// Round 3
// 638.914 us; speedup vs baseline: 1.3689x; 1.3689x over previous
//
#include <hip/hip_runtime.h>

#define NR 64          // NX == NY
#define NH 256         // H
#define NP1 65
#define NITER 20

typedef _Float16 f16x8 __attribute__((ext_vector_type(8)));
typedef _Float16 f16x4 __attribute__((ext_vector_type(4)));
typedef float f32x4t __attribute__((ext_vector_type(4)));

__device__ __forceinline__ float dot4(float4 a, float4 b) {
  return a.x * b.x + a.y * b.y + a.z * b.z + a.w * b.w;
}

__global__ __launch_bounds__(256, 4)
void sinkhorn_kernel(const float* __restrict__ x, const float* __restrict__ y,
                     const float* __restrict__ gam, const float* __restrict__ bet,
                     const float* __restrict__ wdb, const float* __restrict__ bdb,
                     float* __restrict__ out_match, float* __restrict__ out_score)
{
  const int b    = blockIdx.x;
  const int t    = threadIdx.x;
  const int lane = t & 63;
  const int wvid = t >> 6;      // wave 0..3
  const int ti   = t >> 4;      // 0..15
  const int tj   = t & 15;      // 0..15
  const int i0   = ti * 4, j0 = tj * 4;
  const int ql   = lane >> 4;   // quarter within wave 0..3
  const int pl   = lane & 15;

  // s_buf phases (8192 floats = 32 KB):
  //  P1: As_hi | As_lo | Bs_hi | Bs_lo, each f16[64][64] xor-swizzled (8 KB each)
  //  P2: Cf f32 [64][68] = floats 0..4351 (aliases staging)
  //  P3: vp[2][4][64] at 4352, vp64[2][4] at 4864
  //  P4: Om[65*65] output staging (aliases Cf)
  __shared__ __align__(16) float s_buf[8192];
  __shared__ __align__(16) float s_gw[NH];
  __shared__ __align__(16) float s_sx[NR], s_ax[NR], s_sy[NR], s_ay[NR];
  __shared__ float s_red[8];
  __shared__ float s_S12[2];

  char* As_hi = (char*)s_buf;                 // 8 KB
  char* As_lo = (char*)s_buf + 8192;
  char* Bs_hi = (char*)s_buf + 16384;
  char* Bs_lo = (char*)s_buf + 24576;
  float* Cf   = s_buf;                        // [64][68]
  float* vp   = s_buf + 4352;                 // [2][4][64]
  float* vp64 = s_buf + 4864;                 // [2][4]
  float* Om   = s_buf;                        // [4225]

  const float norm_c  = -4.852030263919617f;    // -log(128); exp = 1/128
  const float logmu64 = -0.6931471805599453f;   // -log2; exp = 0.5

  // ---------------- phase 0: gw = gamma*w, S1 = sum(gw), S2 = sum(beta*w)+b
  {
    float gv = gam[t];
    float wv = wdb[t];
    float p1 = gv * wv;
    float p2 = bet[t] * wv;
    s_gw[t] = p1;
    #pragma unroll
    for (int o = 1; o < 64; o <<= 1) { p1 += __shfl_xor(p1, o); p2 += __shfl_xor(p2, o); }
    if (lane == 0) { s_red[wvid * 2] = p1; s_red[wvid * 2 + 1] = p2; }
  }
  __syncthreads();
  if (t == 0) {
    s_S12[0] = s_red[0] + s_red[2] + s_red[4] + s_red[6];
    s_S12[1] = s_red[1] + s_red[3] + s_red[5] + s_red[7] + bdb[0];
  }

  // ---------------- phase 1: load + stats (f32) + split-f16 staging + MFMA
  float xsum[4] = {}, xsq[4] = {}, xdg[4] = {};
  float ysum[4] = {}, ysq[4] = {}, ydg[4] = {};
  f32x4t acc4[4];
  #pragma unroll
  for (int ct = 0; ct < 4; ++ct) {
    #pragma unroll
    for (int r = 0; r < 4; ++r) acc4[ct][r] = 0.0f;
  }

  const size_t gbase = (size_t)b * NR * NH;
  const int lh4 = tj * 4;      // h-offset within 64-float chunk

  for (int ch = 0; ch < 4; ++ch) {
    __syncthreads();   // previous chunk's fragment reads done before overwrite
    const float4 gw4 = *(const float4*)(s_gw + ch * 64 + lh4);
    #pragma unroll
    for (int j = 0; j < 4; ++j) {
      const int row  = ti + 16 * j;
      const int blk  = (tj >> 1) ^ (row & 7);          // xor-swizzled 16B block
      const int boff = row * 128 + blk * 16 + (tj & 1) * 8;
      const float4 xv = *(const float4*)(x + gbase + (size_t)row * NH + ch * 64 + lh4);
      xsum[j] += xv.x + xv.y + xv.z + xv.w;
      xsq[j]  += dot4(xv, xv);
      xdg[j]  += dot4(xv, gw4);
      f16x4 xh, xl;
      xh[0] = (_Float16)xv.x; xh[1] = (_Float16)xv.y;
      xh[2] = (_Float16)xv.z; xh[3] = (_Float16)xv.w;
      xl[0] = (_Float16)(xv.x - (float)xh[0]);
      xl[1] = (_Float16)(xv.y - (float)xh[1]);
      xl[2] = (_Float16)(xv.z - (float)xh[2]);
      xl[3] = (_Float16)(xv.w - (float)xh[3]);
      *(f16x4*)(As_hi + boff) = xh;
      *(f16x4*)(As_lo + boff) = xl;
      const float4 yv = *(const float4*)(y + gbase + (size_t)row * NH + ch * 64 + lh4);
      ysum[j] += yv.x + yv.y + yv.z + yv.w;
      ysq[j]  += dot4(yv, yv);
      ydg[j]  += dot4(yv, gw4);
      f16x4 yh, yl;
      yh[0] = (_Float16)yv.x; yh[1] = (_Float16)yv.y;
      yh[2] = (_Float16)yv.z; yh[3] = (_Float16)yv.w;
      yl[0] = (_Float16)(yv.x - (float)yh[0]);
      yl[1] = (_Float16)(yv.y - (float)yh[1]);
      yl[2] = (_Float16)(yv.z - (float)yh[2]);
      yl[3] = (_Float16)(yv.w - (float)yh[3]);
      *(f16x4*)(Bs_hi + boff) = yh;
      *(f16x4*)(Bs_lo + boff) = yl;
    }
    __syncthreads();
    // wave wvid: A rows 16w..16w+15, K-steps of 32 within the chunk
    #pragma unroll
    for (int s = 0; s < 2; ++s) {
      const int arow = 16 * wvid + pl;
      const int kb   = 4 * s + ql;                     // 16B-block index in row
      const int ab   = kb ^ (pl & 7);                  // arow&7 == pl&7
      const int aoff = arow * 128 + ab * 16;
      const f16x8 afh = *(const f16x8*)(As_hi + aoff);
      const f16x8 afl = *(const f16x8*)(As_lo + aoff);
      #pragma unroll
      for (int ct = 0; ct < 4; ++ct) {
        const int boff2 = (16 * ct + pl) * 128 + ab * 16;   // bcol&7 == pl&7
        const f16x8 bfh = *(const f16x8*)(Bs_hi + boff2);
        const f16x8 bfl = *(const f16x8*)(Bs_lo + boff2);
        acc4[ct] = __builtin_amdgcn_mfma_f32_16x16x32_f16(afh, bfh, acc4[ct], 0, 0, 0);
        acc4[ct] = __builtin_amdgcn_mfma_f32_16x16x32_f16(afh, bfl, acc4[ct], 0, 0, 0);
        acc4[ct] = __builtin_amdgcn_mfma_f32_16x16x32_f16(afl, bfh, acc4[ct], 0, 0, 0);
      }
    }
  }

  // reduce stats across the 16 tj lanes sharing the same row set
  #pragma unroll
  for (int o = 1; o < 16; o <<= 1) {
    #pragma unroll
    for (int j = 0; j < 4; ++j) {
      xsum[j] += __shfl_xor(xsum[j], o);
      xsq[j]  += __shfl_xor(xsq[j], o);
      xdg[j]  += __shfl_xor(xdg[j], o);
      ysum[j] += __shfl_xor(ysum[j], o);
      ysq[j]  += __shfl_xor(ysq[j], o);
      ydg[j]  += __shfl_xor(ydg[j], o);
    }
  }
  if (tj == 0) {
    const float S1 = s_S12[0], S2 = s_S12[1];
    #pragma unroll
    for (int j = 0; j < 4; ++j) {
      const int r = ti + 16 * j;
      float mu   = xsum[j] * (1.0f / NH);
      float var  = xsq[j] * (1.0f / NH) - mu * mu;
      float rstd = rsqrtf(var + 1e-5f);
      s_ax[r] = tanhf(rstd * (xdg[j] - mu * S1) + S2);
      s_sx[r] = 1.0f / fmaxf(sqrtf(xsq[j]), 1e-12f);
      mu   = ysum[j] * (1.0f / NH);
      var  = ysq[j] * (1.0f / NH) - mu * mu;
      rstd = rsqrtf(var + 1e-5f);
      s_ay[r] = tanhf(rstd * (ydg[j] - mu * S1) + S2);
      s_sy[r] = 1.0f / fmaxf(sqrtf(ysq[j]), 1e-12f);
    }
  }
  __syncthreads();   // stats visible; all fragment reads complete -> alias Cf

  // ---------------- scatter MFMA accumulators: D col=lane&15, row=(lane>>4)*4+reg
  #pragma unroll
  for (int ct = 0; ct < 4; ++ct) {
    #pragma unroll
    for (int r = 0; r < 4; ++r) {
      Cf[(16 * wvid + 4 * ql + r) * 68 + 16 * ct + pl] = acc4[ct][r];
    }
  }
  __syncthreads();

  // ---------------- gather 4x4 tile; C = couplings/reg and E = exp(C) in regs
  const float4 sx4 = *(const float4*)(s_sx + i0);
  const float4 sy4 = *(const float4*)(s_sy + j0);
  const float4 ax4 = *(const float4*)(s_ax + i0);
  const float4 ay4 = *(const float4*)(s_ay + j0);
  const float sxr[4] = {sx4.x, sx4.y, sx4.z, sx4.w};
  const float syc[4] = {sy4.x, sy4.y, sy4.z, sy4.w};
  float C[4][4], E[4][4];
  #pragma unroll
  for (int r = 0; r < 4; ++r) {
    const float4 c4 = *(const float4*)(Cf + (i0 + r) * 68 + j0);
    const float cr[4] = {c4.x, c4.y, c4.z, c4.w};
    #pragma unroll
    for (int c = 0; c < 4; ++c) {
      C[r][c] = cr[c] * sxr[r] * syc[c] * 10.0f;   // /REG
      E[r][c] = __expf(C[r][c]);
    }
  }
  const float exi64[4] = {__expf(10.0f * ax4.x), __expf(10.0f * ax4.y),
                          __expf(10.0f * ax4.z), __expf(10.0f * ax4.w)};
  const float ey64[4]  = {__expf(10.0f * ay4.x), __expf(10.0f * ay4.y),
                          __expf(10.0f * ay4.z), __expf(10.0f * ay4.w)};

  // ---------------- Sinkhorn: 20 iterations, all state in registers.
  float ev_c[4] = {1.0f, 1.0f, 1.0f, 1.0f};
  float ev64 = 1.0f;
  float eu_r[4];
  float eu64 = 1.0f;
  float su_s[4], p64_s, sv_s[4], rs_s;
  int bufo = 0;

  #pragma unroll 2
  for (int it = 0; it < NITER; ++it) {
    // ---- u update (exp domain)
    float s0 = E[0][0] * ev_c[0] + E[0][1] * ev_c[1] + E[0][2] * ev_c[2] + E[0][3] * ev_c[3];
    float s1 = E[1][0] * ev_c[0] + E[1][1] * ev_c[1] + E[1][2] * ev_c[2] + E[1][3] * ev_c[3];
    float s2 = E[2][0] * ev_c[0] + E[2][1] * ev_c[1] + E[2][2] * ev_c[2] + E[2][3] * ev_c[3];
    float s3 = E[3][0] * ev_c[0] + E[3][1] * ev_c[1] + E[3][2] * ev_c[2] + E[3][3] * ev_c[3];
    float p64 = ey64[0] * ev_c[0] + ey64[1] * ev_c[1] + ey64[2] * ev_c[2] + ey64[3] * ev_c[3];
    #pragma unroll
    for (int o = 1; o < 16; o <<= 1) {
      s0  += __shfl_xor(s0, o);
      s1  += __shfl_xor(s1, o);
      s2  += __shfl_xor(s2, o);
      s3  += __shfl_xor(s3, o);
      p64 += __shfl_xor(p64, o);
    }
    su_s[0] = s0 + exi64[0] * ev64;
    su_s[1] = s1 + exi64[1] * ev64;
    su_s[2] = s2 + exi64[2] * ev64;
    su_s[3] = s3 + exi64[3] * ev64;
    p64_s = p64;
    eu_r[0] = 0.0078125f * __builtin_amdgcn_rcpf(su_s[0]);
    eu_r[1] = 0.0078125f * __builtin_amdgcn_rcpf(su_s[1]);
    eu_r[2] = 0.0078125f * __builtin_amdgcn_rcpf(su_s[2]);
    eu_r[3] = 0.0078125f * __builtin_amdgcn_rcpf(su_s[3]);
    eu64    = 0.5f       * __builtin_amdgcn_rcpf(p64);

    // ---- v update
    float q0 = E[0][0] * eu_r[0] + E[1][0] * eu_r[1] + E[2][0] * eu_r[2] + E[3][0] * eu_r[3];
    float q1 = E[0][1] * eu_r[0] + E[1][1] * eu_r[1] + E[2][1] * eu_r[2] + E[3][1] * eu_r[3];
    float q2 = E[0][2] * eu_r[0] + E[1][2] * eu_r[1] + E[2][2] * eu_r[2] + E[3][2] * eu_r[3];
    float q3 = E[0][3] * eu_r[0] + E[1][3] * eu_r[1] + E[2][3] * eu_r[2] + E[3][3] * eu_r[3];
    float r64 = exi64[0] * eu_r[0] + exi64[1] * eu_r[1] + exi64[2] * eu_r[2] + exi64[3] * eu_r[3];
    #pragma unroll
    for (int o = 16; o < 64; o <<= 1) {
      q0  += __shfl_xor(q0, o);
      q1  += __shfl_xor(q1, o);
      q2  += __shfl_xor(q2, o);
      q3  += __shfl_xor(q3, o);
      r64 += __shfl_xor(r64, o);
    }
    if ((t & 48) == 0) {   // one 16-lane slice per wave writes the wave partial
      *(float4*)(vp + (bufo * 4 + wvid) * 64 + j0) = make_float4(q0, q1, q2, q3);
      if (tj == 0) vp64[bufo * 4 + wvid] = r64;
    }
    __syncthreads();
    float sv0 = 0.0f, sv1 = 0.0f, sv2 = 0.0f, sv3 = 0.0f;
    #pragma unroll
    for (int w = 0; w < 4; ++w) {
      const float4 qq = *(const float4*)(vp + (bufo * 4 + w) * 64 + j0);
      sv0 += qq.x; sv1 += qq.y; sv2 += qq.z; sv3 += qq.w;
    }
    const float4 rr4 = *(const float4*)(vp64 + bufo * 4);
    rs_s = rr4.x + rr4.y + rr4.z + rr4.w;
    sv_s[0] = sv0 + ey64[0] * eu64;
    sv_s[1] = sv1 + ey64[1] * eu64;
    sv_s[2] = sv2 + ey64[2] * eu64;
    sv_s[3] = sv3 + ey64[3] * eu64;
    ev_c[0] = 0.0078125f * __builtin_amdgcn_rcpf(sv_s[0]);
    ev_c[1] = 0.0078125f * __builtin_amdgcn_rcpf(sv_s[1]);
    ev_c[2] = 0.0078125f * __builtin_amdgcn_rcpf(sv_s[2]);
    ev_c[3] = 0.0078125f * __builtin_amdgcn_rcpf(sv_s[3]);
    ev64    = 0.5f       * __builtin_amdgcn_rcpf(rs_s);
    bufo ^= 1;
  }

  // final u, v in log domain
  float u_r[4], v_c[4];
  #pragma unroll
  for (int r = 0; r < 4; ++r) u_r[r] = norm_c - __logf(su_s[r]);
  #pragma unroll
  for (int c = 0; c < 4; ++c) v_c[c] = norm_c - __logf(sv_s[c]);
  const float u64 = logmu64 - __logf(p64_s);
  const float v64 = logmu64 - __logf(rs_s);

  // ---------------- stage matching tile in LDS (Om aliases Cf) + fused score
  float sacc = 0.0f;
  #pragma unroll
  for (int r = 0; r < 4; ++r) {
    #pragma unroll
    for (int c = 0; c < 4; ++c) {
      const float m = C[r][c] + u_r[r] + v_c[c] - norm_c;
      Om[(i0 + r) * NP1 + (j0 + c)] = m;
      sacc += __expf(m) * C[r][c];   // scores/temp == C (reg==temp)
    }
  }
  if (t < 16) {   // dustbin row 64: thread t owns cols 4t..4t+3 (== j0 here)
    Om[64 * NP1 + j0 + 0] = 10.0f * ay4.x + u64 + v_c[0] - norm_c;
    Om[64 * NP1 + j0 + 1] = 10.0f * ay4.y + u64 + v_c[1] - norm_c;
    Om[64 * NP1 + j0 + 2] = 10.0f * ay4.z + u64 + v_c[2] - norm_c;
    Om[64 * NP1 + j0 + 3] = 10.0f * ay4.w + u64 + v_c[3] - norm_c;
  }
  if (tj == 0) {  // dustbin col 64: rows i0..i0+3
    Om[(i0 + 0) * NP1 + 64] = 10.0f * ax4.x + u_r[0] + v64 - norm_c;
    Om[(i0 + 1) * NP1 + 64] = 10.0f * ax4.y + u_r[1] + v64 - norm_c;
    Om[(i0 + 2) * NP1 + 64] = 10.0f * ax4.z + u_r[2] + v64 - norm_c;
    Om[(i0 + 3) * NP1 + 64] = 10.0f * ax4.w + u_r[3] + v64 - norm_c;
  }
  if (t == 0) {
    Om[64 * NP1 + 64] = -1000.0f + u64 + v64 - norm_c;
  }

  #pragma unroll
  for (int o = 1; o < 64; o <<= 1) sacc += __shfl_xor(sacc, o);
  if (lane == 0) s_red[wvid] = sacc;
  __syncthreads();   // Om + s_red visible

  // coalesced, contiguous copy to global
  const size_t mbase = (size_t)b * (size_t)(NP1 * NP1);
  for (int idx = t; idx < NP1 * NP1; idx += 256) {
    out_match[mbase + idx] = Om[idx];
  }
  if (t == 0) out_score[b] = s_red[0] + s_red[1] + s_red[2] + s_red[3];
}

extern "C" void kernel_launch(void* const* d_in, const int* in_sizes, int n_in,
                              void* d_out, int out_size, void* d_ws, size_t ws_size,
                              hipStream_t stream) {
  const float* x   = (const float*)d_in[0];
  const float* y   = (const float*)d_in[1];
  const float* gam = (const float*)d_in[2];
  const float* bet = (const float*)d_in[3];
  const float* wdb = (const float*)d_in[4];
  const float* bdb = (const float*)d_in[5];
  float* out_match = (float*)d_out;
  float* out_score = (float*)d_out + (size_t)4096 * 4225;
  sinkhorn_kernel<<<4096, 256, 0, stream>>>(x, y, gam, bet, wdb, bdb, out_match, out_score);
}